// Round 8
// baseline (860.055 us; speedup 1.0000x reference)
//
#include <hip/hip_runtime.h>
#include <math.h>

#define B_ 8
#define T_ 12
#define N_ 200
#define R_ 1600    // B*N
#define NN_ 40000  // N*N
#define FTS 201    // sFt row stride (odd -> conflict-free b32 column reads)

__device__ __forceinline__ float sigm(float v) { return 1.f / (1.f + expf(-v)); }

// ======== Phase A: full dy-GRU chain + P/Q projections, 4 rows/block ========
__global__ void __launch_bounds__(256) k_dyall(
        const float* __restrict__ x,  const float* __restrict__ nf,
        const float* __restrict__ Ws2d, const float* __restrict__ bs2d,
        const float* __restrict__ Wrz,  const float* __restrict__ brz,
        const float* __restrict__ Wh,   const float* __restrict__ bh,
        const float* __restrict__ Wc2,  const float* __restrict__ Wm2,
        float* __restrict__ Pc, float* __restrict__ Qc,
        float* __restrict__ Pm, float* __restrict__ Qm,
        float* __restrict__ state) {
    __shared__ float sWs2d[64 * 32], sWrz[33 * 64], sWh[33 * 32];
    __shared__ float sWc2[64 * 32], sWm2[64 * 32];
    __shared__ float sbrz[64], sbh[32], sbs2d[32];
    __shared__ float nfs[4][64], dy[4][32], in1[4][33], in2[4][33], rz[4][64], s4[4][32];
    int bk = blockIdx.x, tid = threadIdx.x;
    int w = tid >> 6, o = tid & 63;
    int row = bk * 4 + w, b = row / N_, n = row % N_;
    state[bk * 256 + tid] = 0.f;
    for (int idx = tid; idx < 2048; idx += 256) sWs2d[idx] = Ws2d[idx];
    for (int idx = tid; idx < 2112; idx += 256) sWrz[idx] = Wrz[idx];
    for (int idx = tid; idx < 1056; idx += 256) sWh[idx] = Wh[idx];
    for (int idx = tid; idx < 2048; idx += 256) { sWc2[idx] = Wc2[idx]; sWm2[idx] = Wm2[idx]; }
    if (tid < 64) sbrz[tid] = brz[tid];
    if (tid < 32) { sbh[tid] = bh[tid]; sbs2d[tid] = bs2d[tid]; }
    nfs[w][o] = nf[n * 64 + o];
    __syncthreads();
    if (o < 32) {
        float acc = sbs2d[o];
        #pragma unroll 8
        for (int i = 0; i < 64; ++i) acc += nfs[w][i] * sWs2d[i * 32 + o];
        dy[w][o] = acc;
    }
    __syncthreads();
    for (int t = 0; t < T_; ++t) {
        if (o == 0) { float v = x[((b * T_ + t) * N_ + n) * 2]; in1[w][0] = v; in2[w][0] = v; }
        if (o < 32) in1[w][o + 1] = dy[w][o];
        __syncthreads();
        float acc = sbrz[o];
        #pragma unroll
        for (int i = 0; i < 33; ++i) acc += in1[w][i] * sWrz[i * 64 + o];
        rz[w][o] = sigm(acc);
        __syncthreads();
        if (o < 32) in2[w][o + 1] = rz[w][o] * dy[w][o];
        __syncthreads();
        if (o < 32) {
            float h = sbh[o];
            #pragma unroll
            for (int i = 0; i < 33; ++i) h += in2[w][i] * sWh[i * 32 + o];
            h = tanhf(h);
            float z = rz[w][32 + o];
            float nd = z * dy[w][o] + (1.f - z) * h;
            dy[w][o] = nd;
            s4[w][o] = nd > 0.f ? nd : 0.f;
        }
        __syncthreads();
        size_t base = ((size_t)t * R_ + row) * 32;
        for (int idx = o; idx < 128; idx += 64) {
            int mat = idx >> 5, k = idx & 31;
            const float* W = (mat < 2) ? sWc2 : sWm2;
            int rb = (mat & 1) ? 32 : 0;
            float a = 0.f;
            #pragma unroll
            for (int i = 0; i < 32; ++i) a += s4[w][i] * W[(rb + i) * 32 + k];
            ((mat == 0) ? Pc : (mat == 1) ? Qc : (mat == 2) ? Pm : Qm)[base + k] = a;
        }
        __syncthreads();
    }
}

// ======== Phase B: all 96 adjacency matrices in parallel ========
__global__ void __launch_bounds__(256) k_pairall(
        const float* __restrict__ Pc, const float* __restrict__ Qc,
        const float* __restrict__ Pm, const float* __restrict__ Qm,
        const float* __restrict__ bc2, const float* __restrict__ Wc1,
        const float* __restrict__ bc1,
        const float* __restrict__ bm2, const float* __restrict__ Wm1,
        const float* __restrict__ bm1,
        float* __restrict__ out) {
    __shared__ float sPc[16][33], sQc[16][33], sPm[16][33], sQm[16][33];
    __shared__ float sbc2[32], sWc1[32], sbm2[32], sWm1[32];
    int z = blockIdx.z;            // t*8 + b
    int i0 = blockIdx.x * 16, j0 = blockIdx.y * 16;
    int tid = threadIdx.y * 16 + threadIdx.x;
    size_t tb = (size_t)z * N_;
    for (int l = tid; l < 512; l += 256) {
        int r = l >> 5, k = l & 31;
        int gi = i0 + r, gj = j0 + r;
        sPc[r][k] = (gi < N_) ? Pc[(tb + gi) * 32 + k] : 0.f;
        sPm[r][k] = (gi < N_) ? Pm[(tb + gi) * 32 + k] : 0.f;
        sQc[r][k] = (gj < N_) ? Qc[(tb + gj) * 32 + k] : 0.f;
        sQm[r][k] = (gj < N_) ? Qm[(tb + gj) * 32 + k] : 0.f;
    }
    if (tid < 32) { sbc2[tid] = bc2[tid]; sWc1[tid] = Wc1[tid];
                    sbm2[tid] = bm2[tid]; sWm1[tid] = Wm1[tid]; }
    __syncthreads();
    int i = i0 + threadIdx.y, j = j0 + threadIdx.x;
    if (i >= N_ || j >= N_) return;
    float g = 0.f, m = 0.f;
    #pragma unroll
    for (int k = 0; k < 32; ++k) {
        float hc = sPc[threadIdx.y][k] + sQc[threadIdx.x][k] + sbc2[k];
        g += (hc > 0.f ? hc : 0.f) * sWc1[k];
        float hm = sPm[threadIdx.y][k] + sQm[threadIdx.x][k] + sbm2[k];
        m += (hm > 0.f ? hm : 0.f) * sWm1[k];
    }
    g += bc1[0];
    m += bm1[0];
    out[R_ + (((size_t)z * N_ + i) * N_ + j)] = g * sigm(m);
}

// ======== A2 = A @ A, VALU-bound: wave=16 rows x 64 lane-cols ========
// A-row operand wave-uniform from global; B strip in LDS stride-1 (no conflicts).
__global__ void __launch_bounds__(256) k_a2(
        const float* __restrict__ Abase, float* __restrict__ Cbase) {
    __shared__ float Bs[200 * 64];      // [k][c] = A[k][j0+c]
    int bx = blockIdx.x;
    int z = bx >> 4, tl = bx & 15;
    int i0 = (tl >> 2) * 64, j0 = (tl & 3) * 64;
    const float* Az = Abase + (size_t)z * NN_;
    float* Cz = Cbase + (size_t)z * NN_;
    int tid = threadIdx.x;
    int w = tid >> 6, c = tid & 63;
    for (int idx = tid; idx < 3200; idx += 256) {
        int k = idx >> 4, cg = idx & 15;
        float4 v = (j0 + 4 * cg < 200)
                 ? *(const float4*)(Az + (size_t)k * 200 + j0 + 4 * cg)
                 : make_float4(0.f, 0.f, 0.f, 0.f);
        *(float4*)&Bs[(k << 6) + 4 * cg] = v;
    }
    __syncthreads();
    int r0 = i0 + w * 16;
    float acc[16];
    #pragma unroll
    for (int i = 0; i < 16; ++i) acc[i] = 0.f;
    for (int kg = 0; kg < 50; ++kg) {
        float fq[4];
        #pragma unroll
        for (int q = 0; q < 4; ++q) fq[q] = Bs[(4 * kg + q) * 64 + c];
        #pragma unroll
        for (int h = 0; h < 2; ++h) {
            float4 av[8];
            #pragma unroll
            for (int rr = 0; rr < 8; ++rr) {
                int r = r0 + h * 8 + rr;
                int rc = r < 200 ? r : 199;          // clamp: stays in-matrix
                av[rr] = *(const float4*)(Az + (size_t)rc * 200 + 4 * kg);
            }
            #pragma unroll
            for (int q = 0; q < 4; ++q) {
                #pragma unroll
                for (int rr = 0; rr < 8; ++rr)
                    acc[h * 8 + rr] += (&av[rr].x)[q] * fq[q];
            }
        }
    }
    if (j0 + c < 200) {
        #pragma unroll
        for (int rr = 0; rr < 16; ++rr) {
            int gi = r0 + rr;
            if (gi < 200) Cz[(size_t)gi * 200 + j0 + c] = acc[rr];
        }
    }
}

// ======== xt-hops: xh[zl][i][4] = {A@x0, A@x1, A2@x0, A2@x1} ========
__global__ void __launch_bounds__(256) k_xh(
        const float* __restrict__ Abase, const float* __restrict__ A2base,
        const float* __restrict__ x, int z0, float* __restrict__ xh) {
    __shared__ float xtl[400];
    int zl = blockIdx.x, tid = threadIdx.x;
    int z = z0 + zl, t = z >> 3, b = z & 7;
    int w = tid >> 6, l = tid & 63;
    const float* xb = x + ((size_t)(b * T_ + t)) * N_ * 2;
    for (int idx = tid; idx < 400; idx += 256) xtl[idx] = xb[idx];
    __syncthreads();
    for (int it = 0; it < 50; ++it) {
        int i = it * 4 + w;
        float p0 = 0.f, p1 = 0.f, p2 = 0.f, p3 = 0.f;
        if (l < 50) {
            float4 a4 = *(const float4*)(Abase + (size_t)zl * NN_ + i * 200 + 4 * l);
            float4 c4 = *(const float4*)(A2base + (size_t)zl * NN_ + i * 200 + 4 * l);
            #pragma unroll
            for (int q = 0; q < 4; ++q) {
                float av = (&a4.x)[q], cv = (&c4.x)[q];
                float x0 = xtl[(4 * l + q) * 2], x1 = xtl[(4 * l + q) * 2 + 1];
                p0 += av * x0; p1 += av * x1; p2 += cv * x0; p3 += cv * x1;
            }
        }
        #pragma unroll
        for (int off = 32; off > 0; off >>= 1) {
            p0 += __shfl_down(p0, off); p1 += __shfl_down(p1, off);
            p2 += __shfl_down(p2, off); p3 += __shfl_down(p3, off);
        }
        if (l == 0) *(float4*)(xh + ((size_t)zl * N_ + i) * 4) = make_float4(p0, p1, p2, p3);
    }
}

// ======== K1: hops + ru gate -> rs, u (8 rows/block) ========
// sFt[c][j] transposed (hop); st8 = own 8 rows row-major (gate).
// g8[r][132] = [Ax0,Ax1,A@S | A2x0,A2x1,A2@S] (reference f order).
__global__ void __launch_bounds__(256) k_ru2(
        const float* __restrict__ At, const float* __restrict__ A2t,
        const float* __restrict__ xht,
        const float* __restrict__ x, int t, const float* __restrict__ state,
        const float* __restrict__ Wru, const float* __restrict__ bru,
        float* __restrict__ rs, float* __restrict__ ub) {
    __shared__ float sFt[64 * FTS];
    __shared__ float st8[8 * 64];
    __shared__ float g8[8 * 132];
    __shared__ float xts[16];
    int bx = blockIdx.x;
    int b = bx / 25, i0 = (bx % 25) * 8;
    int tid = threadIdx.x;
    {
        const float4* stb = (const float4*)(state + (size_t)b * N_ * 64);
        for (int idx = tid; idx < 3200; idx += 256) {
            int j = idx >> 4, cg = idx & 15;
            float4 v = stb[idx];
            sFt[(4 * cg + 0) * FTS + j] = v.x;
            sFt[(4 * cg + 1) * FTS + j] = v.y;
            sFt[(4 * cg + 2) * FTS + j] = v.z;
            sFt[(4 * cg + 3) * FTS + j] = v.w;
        }
        for (int idx = tid; idx < 512; idx += 256)
            st8[idx] = state[((size_t)b * N_ + i0) * 64 + idx];
        if (tid < 16) xts[tid] = x[((size_t)(b * T_ + t) * N_ + i0 + (tid >> 1)) * 2 + (tid & 1)];
        if (tid < 32) {
            int rr = tid >> 2, q = tid & 3;
            g8[rr * 132 + ((q < 2) ? q : q + 64)] = xht[((size_t)b * N_ + i0 + rr) * 4 + q];
        }
    }
    __syncthreads();
    {   // hop: wave w -> mt = w>>1, rows rbase..rbase+3; lane = output col c
        int w = tid >> 6, c = tid & 63;
        int mt = w >> 1, rbase = (w & 1) * 4;
        const float* Am = (mt ? A2t : At) + ((size_t)b * N_ + i0 + rbase) * 200;
        float acc0 = 0.f, acc1 = 0.f, acc2 = 0.f, acc3 = 0.f;
        #pragma unroll 2
        for (int jg = 0; jg < 50; ++jg) {
            float4 a0 = *(const float4*)(Am + 4 * jg);
            float4 a1 = *(const float4*)(Am + 200 + 4 * jg);
            float4 a2 = *(const float4*)(Am + 400 + 4 * jg);
            float4 a3 = *(const float4*)(Am + 600 + 4 * jg);
            #pragma unroll
            for (int q = 0; q < 4; ++q) {
                float f = sFt[c * FTS + 4 * jg + q];
                acc0 += (&a0.x)[q] * f;
                acc1 += (&a1.x)[q] * f;
                acc2 += (&a2.x)[q] * f;
                acc3 += (&a3.x)[q] * f;
            }
        }
        float* gr = &g8[(rbase) * 132 + 2 + mt * 66 + c];
        gr[0] = acc0; gr[132] = acc1; gr[264] = acc2; gr[396] = acc3;
    }
    __syncthreads();
    {   // ru gate: thread = 2 rows x 2 cols (c, c+64); wave reads each f-row once
        int c = tid & 63, rp = tid >> 6;
        int r0 = rp * 2, r1 = r0 + 1;
        float a00 = bru[c], a01 = bru[c + 64];
        float a10 = a00, a11 = a01;
        #pragma unroll
        for (int k = 0; k < 2; ++k) {
            float w0 = Wru[k * 128 + c], w1 = Wru[k * 128 + c + 64];
            float f0 = xts[r0 * 2 + k], f1 = xts[r1 * 2 + k];
            a00 += f0 * w0; a01 += f0 * w1; a10 += f1 * w0; a11 += f1 * w1;
        }
        #pragma unroll 4
        for (int kg = 0; kg < 16; ++kg) {
            float4 f0 = *(const float4*)&st8[r0 * 64 + 4 * kg];
            float4 f1 = *(const float4*)&st8[r1 * 64 + 4 * kg];
            const float* Wp = Wru + (2 + 4 * kg) * 128;
            #pragma unroll
            for (int q = 0; q < 4; ++q) {
                float w0 = Wp[q * 128 + c], w1 = Wp[q * 128 + c + 64];
                float e0 = (&f0.x)[q], e1 = (&f1.x)[q];
                a00 += e0 * w0; a01 += e0 * w1; a10 += e1 * w0; a11 += e1 * w1;
            }
        }
        #pragma unroll 4
        for (int kg = 0; kg < 33; ++kg) {
            float4 f0 = *(const float4*)&g8[r0 * 132 + 4 * kg];
            float4 f1 = *(const float4*)&g8[r1 * 132 + 4 * kg];
            const float* Wp = Wru + (66 + 4 * kg) * 128;
            #pragma unroll
            for (int q = 0; q < 4; ++q) {
                float w0 = Wp[q * 128 + c], w1 = Wp[q * 128 + c + 64];
                float e0 = (&f0.x)[q], e1 = (&f1.x)[q];
                a00 += e0 * w0; a01 += e0 * w1; a10 += e1 * w0; a11 += e1 * w1;
            }
        }
        size_t gr0 = (size_t)b * N_ + i0 + r0, gr1 = gr0 + 1;
        rs[gr0 * 64 + c] = sigm(a00) * st8[r0 * 64 + c];
        rs[gr1 * 64 + c] = sigm(a10) * st8[r1 * 64 + c];
        ub[gr0 * 64 + c] = sigm(a01);
        ub[gr1 * 64 + c] = sigm(a11);
    }
}

// ======== K2: hops + cand gate + state update (8 rows/block) ========
__global__ void __launch_bounds__(256) k_cand2(
        const float* __restrict__ At, const float* __restrict__ A2t,
        const float* __restrict__ xht,
        const float* __restrict__ x, int t, const float* __restrict__ rsin,
        const float* __restrict__ Wcd, const float* __restrict__ bcd,
        const float* __restrict__ ub, float* __restrict__ state) {
    __shared__ float sFt[64 * FTS];
    __shared__ float st8[8 * 64];
    __shared__ float g8[8 * 132];
    __shared__ float xts[16];
    int bx = blockIdx.x;
    int b = bx / 25, i0 = (bx % 25) * 8;
    int tid = threadIdx.x;
    {
        const float4* rbv = (const float4*)(rsin + (size_t)b * N_ * 64);
        for (int idx = tid; idx < 3200; idx += 256) {
            int j = idx >> 4, cg = idx & 15;
            float4 v = rbv[idx];
            sFt[(4 * cg + 0) * FTS + j] = v.x;
            sFt[(4 * cg + 1) * FTS + j] = v.y;
            sFt[(4 * cg + 2) * FTS + j] = v.z;
            sFt[(4 * cg + 3) * FTS + j] = v.w;
        }
        for (int idx = tid; idx < 512; idx += 256)
            st8[idx] = rsin[((size_t)b * N_ + i0) * 64 + idx];
        if (tid < 16) xts[tid] = x[((size_t)(b * T_ + t) * N_ + i0 + (tid >> 1)) * 2 + (tid & 1)];
        if (tid < 32) {
            int rr = tid >> 2, q = tid & 3;
            g8[rr * 132 + ((q < 2) ? q : q + 64)] = xht[((size_t)b * N_ + i0 + rr) * 4 + q];
        }
    }
    __syncthreads();
    {   // hop (identical structure, F = rs)
        int w = tid >> 6, c = tid & 63;
        int mt = w >> 1, rbase = (w & 1) * 4;
        const float* Am = (mt ? A2t : At) + ((size_t)b * N_ + i0 + rbase) * 200;
        float acc0 = 0.f, acc1 = 0.f, acc2 = 0.f, acc3 = 0.f;
        #pragma unroll 2
        for (int jg = 0; jg < 50; ++jg) {
            float4 a0 = *(const float4*)(Am + 4 * jg);
            float4 a1 = *(const float4*)(Am + 200 + 4 * jg);
            float4 a2 = *(const float4*)(Am + 400 + 4 * jg);
            float4 a3 = *(const float4*)(Am + 600 + 4 * jg);
            #pragma unroll
            for (int q = 0; q < 4; ++q) {
                float f = sFt[c * FTS + 4 * jg + q];
                acc0 += (&a0.x)[q] * f;
                acc1 += (&a1.x)[q] * f;
                acc2 += (&a2.x)[q] * f;
                acc3 += (&a3.x)[q] * f;
            }
        }
        float* gr = &g8[(rbase) * 132 + 2 + mt * 66 + c];
        gr[0] = acc0; gr[132] = acc1; gr[264] = acc2; gr[396] = acc3;
    }
    __syncthreads();
    {   // cand gate: thread = 2 rows x 1 col; each wave reads its 2 rows' f once
        int c = tid & 63, rq = tid >> 6;
        int r0 = rq * 2, r1 = r0 + 1;
        float a0 = bcd[c], a1 = a0;
        #pragma unroll
        for (int k = 0; k < 2; ++k) {
            float wv = Wcd[k * 64 + c];
            a0 += xts[r0 * 2 + k] * wv;
            a1 += xts[r1 * 2 + k] * wv;
        }
        #pragma unroll 4
        for (int kg = 0; kg < 16; ++kg) {
            float4 f0 = *(const float4*)&st8[r0 * 64 + 4 * kg];
            float4 f1 = *(const float4*)&st8[r1 * 64 + 4 * kg];
            const float* Wp = Wcd + (2 + 4 * kg) * 64;
            #pragma unroll
            for (int q = 0; q < 4; ++q) {
                float wv = Wp[q * 64 + c];
                a0 += (&f0.x)[q] * wv;
                a1 += (&f1.x)[q] * wv;
            }
        }
        #pragma unroll 4
        for (int kg = 0; kg < 33; ++kg) {
            float4 f0 = *(const float4*)&g8[r0 * 132 + 4 * kg];
            float4 f1 = *(const float4*)&g8[r1 * 132 + 4 * kg];
            const float* Wp = Wcd + (66 + 4 * kg) * 64;
            #pragma unroll
            for (int q = 0; q < 4; ++q) {
                float wv = Wp[q * 64 + c];
                a0 += (&f0.x)[q] * wv;
                a1 += (&f1.x)[q] * wv;
            }
        }
        size_t gr0 = (size_t)b * N_ + i0 + r0, gr1 = gr0 + 1;
        float c0 = tanhf(a0), c1 = tanhf(a1);
        float u0 = ub[gr0 * 64 + c], u1 = ub[gr1 * 64 + c];
        float s0 = state[gr0 * 64 + c], s1 = state[gr1 * 64 + c];
        state[gr0 * 64 + c] = u0 * s0 + (1.f - u0) * c0;
        state[gr1 * 64 + c] = u1 * s1 + (1.f - u1) * c1;
    }
}

// ======== pred head ========
__global__ void __launch_bounds__(64) k_pred(
        const float* __restrict__ state,
        const float* __restrict__ Wp1, const float* __restrict__ bp1,
        const float* __restrict__ Wp2, const float* __restrict__ bp2,
        float* __restrict__ out) {
    __shared__ float st[64];
    int row = blockIdx.x;
    int tid = threadIdx.x;
    st[tid] = state[row * 64 + tid];
    __syncthreads();
    float acc = bp1[tid];
    #pragma unroll 8
    for (int a = 0; a < 64; ++a) acc += st[a] * Wp1[a * 64 + tid];
    acc = acc > 0.f ? acc : 0.01f * acc;
    float v = acc * Wp2[tid];
    #pragma unroll
    for (int off = 32; off > 0; off >>= 1) v += __shfl_down(v, off);
    if (tid == 0) out[row] = v + bp2[0];
}

extern "C" void kernel_launch(void* const* d_in, const int* in_sizes, int n_in,
                              void* d_out, int out_size, void* d_ws, size_t ws_size,
                              hipStream_t stream) {
    const float* x    = (const float*)d_in[0];
    const float* nf   = (const float*)d_in[1];
    const float* Ws2d = (const float*)d_in[2];
    const float* bs2d = (const float*)d_in[3];
    const float* Wrz  = (const float*)d_in[4];
    const float* brz  = (const float*)d_in[5];
    const float* Wh   = (const float*)d_in[6];
    const float* bh   = (const float*)d_in[7];
    const float* Wc2  = (const float*)d_in[8];
    const float* bc2  = (const float*)d_in[9];
    const float* Wc1  = (const float*)d_in[10];
    const float* bc1  = (const float*)d_in[11];
    const float* Wm2  = (const float*)d_in[12];
    const float* bm2  = (const float*)d_in[13];
    const float* Wm1  = (const float*)d_in[14];
    const float* bm1  = (const float*)d_in[15];
    const float* Wru  = (const float*)d_in[16];
    const float* bru  = (const float*)d_in[17];
    const float* Wcand= (const float*)d_in[18];
    const float* bcand= (const float*)d_in[19];
    const float* Wp1  = (const float*)d_in[20];
    const float* bp1  = (const float*)d_in[21];
    const float* Wp2  = (const float*)d_in[22];
    const float* bp2  = (const float*)d_in[23];
    float* out = (float*)d_out;

    float* ws = (float*)d_ws;
    const size_t PQ = (size_t)T_ * R_ * 32;
    float* Pc = ws;
    float* Qc = Pc + PQ;
    float* Pm = Qc + PQ;
    float* Qm = Pm + PQ;

    const size_t A2F = (size_t)96 * NN_;
    const size_t XHF = (size_t)96 * N_ * 4;
    const size_t FULL_NEED = (A2F + XHF + 3 * (size_t)R_ * 64) * 4;
    bool full = ws_size >= FULL_NEED;

    const float* Aall = out + R_;

    if (full) {
        float* A2base = ws;                  // aliases dead P/Q after k_pairall
        float* xhbase = ws + A2F;
        float* state  = xhbase + XHF;
        float* rs     = state + (size_t)R_ * 64;
        float* ub     = rs + (size_t)R_ * 64;

        k_dyall<<<400, 256, 0, stream>>>(x, nf, Ws2d, bs2d, Wrz, brz, Wh, bh,
                                         Wc2, Wm2, Pc, Qc, Pm, Qm, state);
        k_pairall<<<dim3(13, 13, 96), dim3(16, 16), 0, stream>>>(
            Pc, Qc, Pm, Qm, bc2, Wc1, bc1, bm2, Wm1, bm1, out);
        k_a2<<<96 * 16, 256, 0, stream>>>(Aall, A2base);
        k_xh<<<96, 256, 0, stream>>>(Aall, A2base, x, 0, xhbase);

        for (int t = 0; t < T_; ++t) {
            const float* At  = Aall + (size_t)t * 8 * NN_;
            const float* A2t = A2base + (size_t)t * 8 * NN_;
            const float* xht = xhbase + (size_t)t * 8 * N_ * 4;
            k_ru2  <<<200, 256, 0, stream>>>(At, A2t, xht, x, t, state, Wru, bru, rs, ub);
            k_cand2<<<200, 256, 0, stream>>>(At, A2t, xht, x, t, rs, Wcand, bcand, ub, state);
        }
        k_pred<<<R_, 64, 0, stream>>>(state, Wp1, bp1, Wp2, bp2, out);
    } else {
        float* A2base = ws + 4 * PQ;
        float* xhbase = A2base + (size_t)8 * NN_;
        float* state  = xhbase + (size_t)8 * N_ * 4;
        float* rs     = state + (size_t)R_ * 64;
        float* ub     = rs + (size_t)R_ * 64;

        k_dyall<<<400, 256, 0, stream>>>(x, nf, Ws2d, bs2d, Wrz, brz, Wh, bh,
                                         Wc2, Wm2, Pc, Qc, Pm, Qm, state);
        k_pairall<<<dim3(13, 13, 96), dim3(16, 16), 0, stream>>>(
            Pc, Qc, Pm, Qm, bc2, Wc1, bc1, bm2, Wm1, bm1, out);
        for (int t = 0; t < T_; ++t) {
            const float* At = Aall + (size_t)t * 8 * NN_;
            k_a2<<<8 * 16, 256, 0, stream>>>(At, A2base);
            k_xh<<<8, 256, 0, stream>>>(At, A2base, x, t * 8, xhbase);
            k_ru2  <<<200, 256, 0, stream>>>(At, A2base, xhbase, x, t, state, Wru, bru, rs, ub);
            k_cand2<<<200, 256, 0, stream>>>(At, A2base, xhbase, x, t, rs, Wcand, bcand, ub, state);
        }
        k_pred<<<R_, 64, 0, stream>>>(state, Wp1, bp1, Wp2, bp2, out);
    }
}

// Round 9
// 610.038 us; speedup vs baseline: 1.4098x; 1.4098x over previous
//
#include <hip/hip_runtime.h>
#include <math.h>

#define B_ 8
#define T_ 12
#define N_ 200
#define R_ 1600    // B*N
#define NN_ 40000  // N*N

__device__ __forceinline__ float sigm(float v) { return 1.f / (1.f + expf(-v)); }

// ======== Phase A: full dy-GRU chain + P/Q projections, 4 rows/block ========
__global__ void __launch_bounds__(256) k_dyall(
        const float* __restrict__ x,  const float* __restrict__ nf,
        const float* __restrict__ Ws2d, const float* __restrict__ bs2d,
        const float* __restrict__ Wrz,  const float* __restrict__ brz,
        const float* __restrict__ Wh,   const float* __restrict__ bh,
        const float* __restrict__ Wc2,  const float* __restrict__ Wm2,
        float* __restrict__ Pc, float* __restrict__ Qc,
        float* __restrict__ Pm, float* __restrict__ Qm,
        float* __restrict__ state) {
    __shared__ float sWs2d[64 * 32], sWrz[33 * 64], sWh[33 * 32];
    __shared__ float sWc2[64 * 32], sWm2[64 * 32];
    __shared__ float sbrz[64], sbh[32], sbs2d[32];
    __shared__ float nfs[4][64], dy[4][32], in1[4][33], in2[4][33], rz[4][64], s4[4][32];
    int bk = blockIdx.x, tid = threadIdx.x;
    int w = tid >> 6, o = tid & 63;
    int row = bk * 4 + w, b = row / N_, n = row % N_;
    state[bk * 256 + tid] = 0.f;
    for (int idx = tid; idx < 2048; idx += 256) sWs2d[idx] = Ws2d[idx];
    for (int idx = tid; idx < 2112; idx += 256) sWrz[idx] = Wrz[idx];
    for (int idx = tid; idx < 1056; idx += 256) sWh[idx] = Wh[idx];
    for (int idx = tid; idx < 2048; idx += 256) { sWc2[idx] = Wc2[idx]; sWm2[idx] = Wm2[idx]; }
    if (tid < 64) sbrz[tid] = brz[tid];
    if (tid < 32) { sbh[tid] = bh[tid]; sbs2d[tid] = bs2d[tid]; }
    nfs[w][o] = nf[n * 64 + o];
    __syncthreads();
    if (o < 32) {
        float acc = sbs2d[o];
        #pragma unroll 8
        for (int i = 0; i < 64; ++i) acc += nfs[w][i] * sWs2d[i * 32 + o];
        dy[w][o] = acc;
    }
    __syncthreads();
    for (int t = 0; t < T_; ++t) {
        if (o == 0) { float v = x[((b * T_ + t) * N_ + n) * 2]; in1[w][0] = v; in2[w][0] = v; }
        if (o < 32) in1[w][o + 1] = dy[w][o];
        __syncthreads();
        float acc = sbrz[o];
        #pragma unroll
        for (int i = 0; i < 33; ++i) acc += in1[w][i] * sWrz[i * 64 + o];
        rz[w][o] = sigm(acc);
        __syncthreads();
        if (o < 32) in2[w][o + 1] = rz[w][o] * dy[w][o];
        __syncthreads();
        if (o < 32) {
            float h = sbh[o];
            #pragma unroll
            for (int i = 0; i < 33; ++i) h += in2[w][i] * sWh[i * 32 + o];
            h = tanhf(h);
            float z = rz[w][32 + o];
            float nd = z * dy[w][o] + (1.f - z) * h;
            dy[w][o] = nd;
            s4[w][o] = nd > 0.f ? nd : 0.f;
        }
        __syncthreads();
        size_t base = ((size_t)t * R_ + row) * 32;
        for (int idx = o; idx < 128; idx += 64) {
            int mat = idx >> 5, k = idx & 31;
            const float* W = (mat < 2) ? sWc2 : sWm2;
            int rb = (mat & 1) ? 32 : 0;
            float a = 0.f;
            #pragma unroll
            for (int i = 0; i < 32; ++i) a += s4[w][i] * W[(rb + i) * 32 + k];
            ((mat == 0) ? Pc : (mat == 1) ? Qc : (mat == 2) ? Pm : Qm)[base + k] = a;
        }
        __syncthreads();
    }
}

// ======== Phase B: all 96 adjacency matrices in parallel ========
__global__ void __launch_bounds__(256) k_pairall(
        const float* __restrict__ Pc, const float* __restrict__ Qc,
        const float* __restrict__ Pm, const float* __restrict__ Qm,
        const float* __restrict__ bc2, const float* __restrict__ Wc1,
        const float* __restrict__ bc1,
        const float* __restrict__ bm2, const float* __restrict__ Wm1,
        const float* __restrict__ bm1,
        float* __restrict__ out) {
    __shared__ float sPc[16][33], sQc[16][33], sPm[16][33], sQm[16][33];
    __shared__ float sbc2[32], sWc1[32], sbm2[32], sWm1[32];
    int z = blockIdx.z;            // t*8 + b
    int i0 = blockIdx.x * 16, j0 = blockIdx.y * 16;
    int tid = threadIdx.y * 16 + threadIdx.x;
    size_t tb = (size_t)z * N_;
    for (int l = tid; l < 512; l += 256) {
        int r = l >> 5, k = l & 31;
        int gi = i0 + r, gj = j0 + r;
        sPc[r][k] = (gi < N_) ? Pc[(tb + gi) * 32 + k] : 0.f;
        sPm[r][k] = (gi < N_) ? Pm[(tb + gi) * 32 + k] : 0.f;
        sQc[r][k] = (gj < N_) ? Qc[(tb + gj) * 32 + k] : 0.f;
        sQm[r][k] = (gj < N_) ? Qm[(tb + gj) * 32 + k] : 0.f;
    }
    if (tid < 32) { sbc2[tid] = bc2[tid]; sWc1[tid] = Wc1[tid];
                    sbm2[tid] = bm2[tid]; sWm1[tid] = Wm1[tid]; }
    __syncthreads();
    int i = i0 + threadIdx.y, j = j0 + threadIdx.x;
    if (i >= N_ || j >= N_) return;
    float g = 0.f, m = 0.f;
    #pragma unroll
    for (int k = 0; k < 32; ++k) {
        float hc = sPc[threadIdx.y][k] + sQc[threadIdx.x][k] + sbc2[k];
        g += (hc > 0.f ? hc : 0.f) * sWc1[k];
        float hm = sPm[threadIdx.y][k] + sQm[threadIdx.x][k] + sbm2[k];
        m += (hm > 0.f ? hm : 0.f) * sWm1[k];
    }
    g += bc1[0];
    m += bm1[0];
    out[R_ + (((size_t)z * N_ + i) * N_ + j)] = g * sigm(m);
}

// ======== A2 = A @ A, tiled GEMM (R5 version; z fast -> XCD-local b) ========
__global__ void __launch_bounds__(256) k_a2(
        const float* __restrict__ Abase, float* __restrict__ Cbase, int nmat) {
    __shared__ float Ast[32][68];   // [k][i]
    __shared__ float Bs[32][68];    // [k][j]
    int bx = blockIdx.x;
    int z = bx % nmat, tl = bx / nmat;
    int i0 = (tl >> 2) * 64, j0 = (tl & 3) * 64;
    const float* Az = Abase + (size_t)z * NN_;
    float* Cz = Cbase + (size_t)z * NN_;
    int tid = threadIdx.x;
    int tx = tid & 15, ty = tid >> 4;
    float acc[4][4] = {};
    for (int k0 = 0; k0 < 200; k0 += 32) {
        for (int idx = tid; idx < 2048; idx += 256) {
            int i = idx >> 5, k = idx & 31;
            Ast[k][i] = (i0 + i < 200 && k0 + k < 200) ? Az[(i0 + i) * 200 + k0 + k] : 0.f;
        }
        for (int idx = tid; idx < 2048; idx += 256) {
            int k = idx >> 6, j = idx & 63;
            Bs[k][j] = (k0 + k < 200 && j0 + j < 200) ? Az[(k0 + k) * 200 + j0 + j] : 0.f;
        }
        __syncthreads();
        #pragma unroll 8
        for (int k = 0; k < 32; ++k) {
            float4 av = *(const float4*)&Ast[k][ty * 4];
            float4 bv = *(const float4*)&Bs[k][tx * 4];
            acc[0][0] += av.x * bv.x; acc[0][1] += av.x * bv.y; acc[0][2] += av.x * bv.z; acc[0][3] += av.x * bv.w;
            acc[1][0] += av.y * bv.x; acc[1][1] += av.y * bv.y; acc[1][2] += av.y * bv.z; acc[1][3] += av.y * bv.w;
            acc[2][0] += av.z * bv.x; acc[2][1] += av.z * bv.y; acc[2][2] += av.z * bv.z; acc[2][3] += av.z * bv.w;
            acc[3][0] += av.w * bv.x; acc[3][1] += av.w * bv.y; acc[3][2] += av.w * bv.z; acc[3][3] += av.w * bv.w;
        }
        __syncthreads();
    }
    #pragma unroll
    for (int i = 0; i < 4; ++i) {
        int gi = i0 + ty * 4 + i;
        if (gi >= 200) break;
        #pragma unroll
        for (int j = 0; j < 4; ++j) {
            int gj = j0 + tx * 4 + j;
            if (gj < 200) Cz[gi * 200 + gj] = acc[i][j];
        }
    }
}

// ======== xt-hops: xh[zl][i][4] = {A@x0, A@x1, A2@x0, A2@x1} ========
__global__ void __launch_bounds__(256) k_xh(
        const float* __restrict__ Abase, const float* __restrict__ A2base,
        const float* __restrict__ x, int z0, float* __restrict__ xh) {
    __shared__ float xtl[400];
    int zl = blockIdx.x, tid = threadIdx.x;
    int z = z0 + zl, t = z >> 3, b = z & 7;
    int w = tid >> 6, l = tid & 63;
    const float* xb = x + ((size_t)(b * T_ + t)) * N_ * 2;
    for (int idx = tid; idx < 400; idx += 256) xtl[idx] = xb[idx];
    __syncthreads();
    for (int it = 0; it < 50; ++it) {
        int i = it * 4 + w;
        float p0 = 0.f, p1 = 0.f, p2 = 0.f, p3 = 0.f;
        if (l < 50) {
            float4 a4 = *(const float4*)(Abase + (size_t)zl * NN_ + i * 200 + 4 * l);
            float4 c4 = *(const float4*)(A2base + (size_t)zl * NN_ + i * 200 + 4 * l);
            #pragma unroll
            for (int q = 0; q < 4; ++q) {
                float av = (&a4.x)[q], cv = (&c4.x)[q];
                float x0 = xtl[(4 * l + q) * 2], x1 = xtl[(4 * l + q) * 2 + 1];
                p0 += av * x0; p1 += av * x1; p2 += cv * x0; p3 += cv * x1;
            }
        }
        #pragma unroll
        for (int off = 32; off > 0; off >>= 1) {
            p0 += __shfl_down(p0, off); p1 += __shfl_down(p1, off);
            p2 += __shfl_down(p2, off); p3 += __shfl_down(p3, off);
        }
        if (l == 0) *(float4*)(xh + ((size_t)zl * N_ + i) * 4) = make_float4(p0, p1, p2, p3);
    }
}

// ======== K1: hops + ru gate -> rs, u (8 rows/block, XCD-swizzled) ========
// sF [200][64] = S; g8[r][132] = [Ax0,Ax1,A@S | A2x0,A2x1,A2@S] (ref order).
__global__ void __launch_bounds__(256) k_ru2(
        const float* __restrict__ At, const float* __restrict__ A2t,
        const float* __restrict__ xht,
        const float* __restrict__ x, int t, const float* __restrict__ state,
        const float* __restrict__ Wru, const float* __restrict__ bru,
        float* __restrict__ rs, float* __restrict__ ub) {
    __shared__ float sF[200 * 64];
    __shared__ float a8[8 * 200], c8[8 * 200];
    __shared__ float g8[8 * 132];
    __shared__ float xts[16];
    int bx = blockIdx.x;
    int b = bx & 7, i0 = (bx >> 3) * 8;      // XCD-local batches
    int tid = threadIdx.x;
    {
        const float4* stb = (const float4*)(state + (size_t)b * N_ * 64);
        float4* sFv = (float4*)sF;
        for (int idx = tid; idx < 3200; idx += 256) sFv[idx] = stb[idx];
        const float4* Ar = (const float4*)(At + ((size_t)b * N_ + i0) * 200);
        const float4* Cr = (const float4*)(A2t + ((size_t)b * N_ + i0) * 200);
        float4* a8v = (float4*)a8; float4* c8v = (float4*)c8;
        for (int idx = tid; idx < 400; idx += 256) { a8v[idx] = Ar[idx]; c8v[idx] = Cr[idx]; }
        if (tid < 16) xts[tid] = x[((size_t)(b * T_ + t) * N_ + i0 + (tid >> 1)) * 2 + (tid & 1)];
        if (tid < 32) {
            int rr = tid >> 2, q = tid & 3;
            g8[rr * 132 + ((q < 2) ? q : q + 64)] = xht[((size_t)b * N_ + i0 + rr) * 4 + q];
        }
    }
    __syncthreads();
    if (tid < 128) {   // hop: r=tid>>4 (row), cg=tid&15 (4 cols), BOTH matrices
        int r = tid >> 4, cg = tid & 15;
        const float* ar = a8 + r * 200;
        const float* cr = c8 + r * 200;
        float4 accA = make_float4(0.f, 0.f, 0.f, 0.f);
        float4 accC = make_float4(0.f, 0.f, 0.f, 0.f);
        #pragma unroll 2
        for (int jg = 0; jg < 50; ++jg) {
            float4 a4 = *(const float4*)&ar[4 * jg];
            float4 c4 = *(const float4*)&cr[4 * jg];
            const float* fb = &sF[(4 * jg) * 64 + 4 * cg];
            float4 v0 = *(const float4*)fb;
            float4 v1 = *(const float4*)(fb + 64);
            float4 v2 = *(const float4*)(fb + 128);
            float4 v3 = *(const float4*)(fb + 192);
            accA.x += a4.x * v0.x + a4.y * v1.x + a4.z * v2.x + a4.w * v3.x;
            accA.y += a4.x * v0.y + a4.y * v1.y + a4.z * v2.y + a4.w * v3.y;
            accA.z += a4.x * v0.z + a4.y * v1.z + a4.z * v2.z + a4.w * v3.z;
            accA.w += a4.x * v0.w + a4.y * v1.w + a4.z * v2.w + a4.w * v3.w;
            accC.x += c4.x * v0.x + c4.y * v1.x + c4.z * v2.x + c4.w * v3.x;
            accC.y += c4.x * v0.y + c4.y * v1.y + c4.z * v2.y + c4.w * v3.y;
            accC.z += c4.x * v0.z + c4.y * v1.z + c4.z * v2.z + c4.w * v3.z;
            accC.w += c4.x * v0.w + c4.y * v1.w + c4.z * v2.w + c4.w * v3.w;
        }
        float* gr = &g8[r * 132 + 2 + 4 * cg];
        gr[0] = accA.x; gr[1] = accA.y; gr[2] = accA.z; gr[3] = accA.w;
        float* gr2 = gr + 66;
        gr2[0] = accC.x; gr2[1] = accC.y; gr2[2] = accC.z; gr2[3] = accC.w;
    }
    __syncthreads();
    {   // gate: c=tid&127, rq=tid>>7 -> rows rq*4+m
        int c = tid & 127, rq = tid >> 7;
        float bv = bru[c];
        float a0 = bv, a1 = bv, a2 = bv, a3 = bv;
        #pragma unroll
        for (int k = 0; k < 2; ++k) {
            float wv = Wru[k * 128 + c];
            a0 += xts[(rq * 4 + 0) * 2 + k] * wv;
            a1 += xts[(rq * 4 + 1) * 2 + k] * wv;
            a2 += xts[(rq * 4 + 2) * 2 + k] * wv;
            a3 += xts[(rq * 4 + 3) * 2 + k] * wv;
        }
        #pragma unroll 4
        for (int kg = 0; kg < 16; ++kg) {
            float4 f0 = *(const float4*)&sF[(i0 + rq * 4 + 0) * 64 + 4 * kg];
            float4 f1 = *(const float4*)&sF[(i0 + rq * 4 + 1) * 64 + 4 * kg];
            float4 f2 = *(const float4*)&sF[(i0 + rq * 4 + 2) * 64 + 4 * kg];
            float4 f3 = *(const float4*)&sF[(i0 + rq * 4 + 3) * 64 + 4 * kg];
            const float* Wp = Wru + (2 + 4 * kg) * 128 + c;
            float w0 = Wp[0], w1 = Wp[128], w2 = Wp[256], w3 = Wp[384];
            a0 += f0.x * w0 + f0.y * w1 + f0.z * w2 + f0.w * w3;
            a1 += f1.x * w0 + f1.y * w1 + f1.z * w2 + f1.w * w3;
            a2 += f2.x * w0 + f2.y * w1 + f2.z * w2 + f2.w * w3;
            a3 += f3.x * w0 + f3.y * w1 + f3.z * w2 + f3.w * w3;
        }
        #pragma unroll 4
        for (int kg = 0; kg < 33; ++kg) {
            float4 f0 = *(const float4*)&g8[(rq * 4 + 0) * 132 + 4 * kg];
            float4 f1 = *(const float4*)&g8[(rq * 4 + 1) * 132 + 4 * kg];
            float4 f2 = *(const float4*)&g8[(rq * 4 + 2) * 132 + 4 * kg];
            float4 f3 = *(const float4*)&g8[(rq * 4 + 3) * 132 + 4 * kg];
            const float* Wp = Wru + (66 + 4 * kg) * 128 + c;
            float w0 = Wp[0], w1 = Wp[128], w2 = Wp[256], w3 = Wp[384];
            a0 += f0.x * w0 + f0.y * w1 + f0.z * w2 + f0.w * w3;
            a1 += f1.x * w0 + f1.y * w1 + f1.z * w2 + f1.w * w3;
            a2 += f2.x * w0 + f2.y * w1 + f2.z * w2 + f2.w * w3;
            a3 += f3.x * w0 + f3.y * w1 + f3.z * w2 + f3.w * w3;
        }
        float vv[4] = { sigm(a0), sigm(a1), sigm(a2), sigm(a3) };
        #pragma unroll
        for (int m = 0; m < 4; ++m) {
            int lr = rq * 4 + m;
            size_t gr = (size_t)b * N_ + i0 + lr;
            if (c < 64) rs[gr * 64 + c] = vv[m] * sF[(i0 + lr) * 64 + c];
            else        ub[gr * 64 + (c - 64)] = vv[m];
        }
    }
}

// ======== K2: hops + cand gate + state update (8 rows/block) ========
__global__ void __launch_bounds__(256) k_cand2(
        const float* __restrict__ At, const float* __restrict__ A2t,
        const float* __restrict__ xht,
        const float* __restrict__ x, int t, const float* __restrict__ rsin,
        const float* __restrict__ Wcd, const float* __restrict__ bcd,
        const float* __restrict__ ub, float* __restrict__ state) {
    __shared__ float sF[200 * 64];
    __shared__ float a8[8 * 200], c8[8 * 200];
    __shared__ float g8[8 * 132];
    __shared__ float xts[16];
    int bx = blockIdx.x;
    int b = bx & 7, i0 = (bx >> 3) * 8;      // XCD-local batches
    int tid = threadIdx.x;
    {
        const float4* rbv = (const float4*)(rsin + (size_t)b * N_ * 64);
        float4* sFv = (float4*)sF;
        for (int idx = tid; idx < 3200; idx += 256) sFv[idx] = rbv[idx];
        const float4* Ar = (const float4*)(At + ((size_t)b * N_ + i0) * 200);
        const float4* Cr = (const float4*)(A2t + ((size_t)b * N_ + i0) * 200);
        float4* a8v = (float4*)a8; float4* c8v = (float4*)c8;
        for (int idx = tid; idx < 400; idx += 256) { a8v[idx] = Ar[idx]; c8v[idx] = Cr[idx]; }
        if (tid < 16) xts[tid] = x[((size_t)(b * T_ + t) * N_ + i0 + (tid >> 1)) * 2 + (tid & 1)];
        if (tid < 32) {
            int rr = tid >> 2, q = tid & 3;
            g8[rr * 132 + ((q < 2) ? q : q + 64)] = xht[((size_t)b * N_ + i0 + rr) * 4 + q];
        }
    }
    __syncthreads();
    if (tid < 128) {   // hop, both matrices
        int r = tid >> 4, cg = tid & 15;
        const float* ar = a8 + r * 200;
        const float* cr = c8 + r * 200;
        float4 accA = make_float4(0.f, 0.f, 0.f, 0.f);
        float4 accC = make_float4(0.f, 0.f, 0.f, 0.f);
        #pragma unroll 2
        for (int jg = 0; jg < 50; ++jg) {
            float4 a4 = *(const float4*)&ar[4 * jg];
            float4 c4 = *(const float4*)&cr[4 * jg];
            const float* fb = &sF[(4 * jg) * 64 + 4 * cg];
            float4 v0 = *(const float4*)fb;
            float4 v1 = *(const float4*)(fb + 64);
            float4 v2 = *(const float4*)(fb + 128);
            float4 v3 = *(const float4*)(fb + 192);
            accA.x += a4.x * v0.x + a4.y * v1.x + a4.z * v2.x + a4.w * v3.x;
            accA.y += a4.x * v0.y + a4.y * v1.y + a4.z * v2.y + a4.w * v3.y;
            accA.z += a4.x * v0.z + a4.y * v1.z + a4.z * v2.z + a4.w * v3.z;
            accA.w += a4.x * v0.w + a4.y * v1.w + a4.z * v2.w + a4.w * v3.w;
            accC.x += c4.x * v0.x + c4.y * v1.x + c4.z * v2.x + c4.w * v3.x;
            accC.y += c4.x * v0.y + c4.y * v1.y + c4.z * v2.y + c4.w * v3.y;
            accC.z += c4.x * v0.z + c4.y * v1.z + c4.z * v2.z + c4.w * v3.z;
            accC.w += c4.x * v0.w + c4.y * v1.w + c4.z * v2.w + c4.w * v3.w;
        }
        float* gr = &g8[r * 132 + 2 + 4 * cg];
        gr[0] = accA.x; gr[1] = accA.y; gr[2] = accA.z; gr[3] = accA.w;
        float* gr2 = gr + 66;
        gr2[0] = accC.x; gr2[1] = accC.y; gr2[2] = accC.z; gr2[3] = accC.w;
    }
    __syncthreads();
    {   // gate: c=tid&63, rq=tid>>6 -> rows rq*2+m
        int c = tid & 63, rq = tid >> 6;
        float bv = bcd[c];
        float a0 = bv, a1 = bv;
        #pragma unroll
        for (int k = 0; k < 2; ++k) {
            float wv = Wcd[k * 64 + c];
            a0 += xts[(rq * 2 + 0) * 2 + k] * wv;
            a1 += xts[(rq * 2 + 1) * 2 + k] * wv;
        }
        #pragma unroll 4
        for (int kg = 0; kg < 16; ++kg) {
            float4 f0 = *(const float4*)&sF[(i0 + rq * 2 + 0) * 64 + 4 * kg];
            float4 f1 = *(const float4*)&sF[(i0 + rq * 2 + 1) * 64 + 4 * kg];
            const float* Wp = Wcd + (2 + 4 * kg) * 64 + c;
            float w0 = Wp[0], w1 = Wp[64], w2 = Wp[128], w3 = Wp[192];
            a0 += f0.x * w0 + f0.y * w1 + f0.z * w2 + f0.w * w3;
            a1 += f1.x * w0 + f1.y * w1 + f1.z * w2 + f1.w * w3;
        }
        #pragma unroll 4
        for (int kg = 0; kg < 33; ++kg) {
            float4 f0 = *(const float4*)&g8[(rq * 2 + 0) * 132 + 4 * kg];
            float4 f1 = *(const float4*)&g8[(rq * 2 + 1) * 132 + 4 * kg];
            const float* Wp = Wcd + (66 + 4 * kg) * 64 + c;
            float w0 = Wp[0], w1 = Wp[64], w2 = Wp[128], w3 = Wp[192];
            a0 += f0.x * w0 + f0.y * w1 + f0.z * w2 + f0.w * w3;
            a1 += f1.x * w0 + f1.y * w1 + f1.z * w2 + f1.w * w3;
        }
        #pragma unroll
        for (int m = 0; m < 2; ++m) {
            int lr = rq * 2 + m;
            size_t gr = (size_t)b * N_ + i0 + lr;
            float cnd = tanhf(m == 0 ? a0 : a1);
            float u = ub[gr * 64 + c];
            float st = state[gr * 64 + c];
            state[gr * 64 + c] = u * st + (1.f - u) * cnd;
        }
    }
}

// ======== pred head ========
__global__ void __launch_bounds__(64) k_pred(
        const float* __restrict__ state,
        const float* __restrict__ Wp1, const float* __restrict__ bp1,
        const float* __restrict__ Wp2, const float* __restrict__ bp2,
        float* __restrict__ out) {
    __shared__ float st[64];
    int row = blockIdx.x;
    int tid = threadIdx.x;
    st[tid] = state[row * 64 + tid];
    __syncthreads();
    float acc = bp1[tid];
    #pragma unroll 8
    for (int a = 0; a < 64; ++a) acc += st[a] * Wp1[a * 64 + tid];
    acc = acc > 0.f ? acc : 0.01f * acc;
    float v = acc * Wp2[tid];
    #pragma unroll
    for (int off = 32; off > 0; off >>= 1) v += __shfl_down(v, off);
    if (tid == 0) out[row] = v + bp2[0];
}

extern "C" void kernel_launch(void* const* d_in, const int* in_sizes, int n_in,
                              void* d_out, int out_size, void* d_ws, size_t ws_size,
                              hipStream_t stream) {
    const float* x    = (const float*)d_in[0];
    const float* nf   = (const float*)d_in[1];
    const float* Ws2d = (const float*)d_in[2];
    const float* bs2d = (const float*)d_in[3];
    const float* Wrz  = (const float*)d_in[4];
    const float* brz  = (const float*)d_in[5];
    const float* Wh   = (const float*)d_in[6];
    const float* bh   = (const float*)d_in[7];
    const float* Wc2  = (const float*)d_in[8];
    const float* bc2  = (const float*)d_in[9];
    const float* Wc1  = (const float*)d_in[10];
    const float* bc1  = (const float*)d_in[11];
    const float* Wm2  = (const float*)d_in[12];
    const float* bm2  = (const float*)d_in[13];
    const float* Wm1  = (const float*)d_in[14];
    const float* bm1  = (const float*)d_in[15];
    const float* Wru  = (const float*)d_in[16];
    const float* bru  = (const float*)d_in[17];
    const float* Wcand= (const float*)d_in[18];
    const float* bcand= (const float*)d_in[19];
    const float* Wp1  = (const float*)d_in[20];
    const float* bp1  = (const float*)d_in[21];
    const float* Wp2  = (const float*)d_in[22];
    const float* bp2  = (const float*)d_in[23];
    float* out = (float*)d_out;

    float* ws = (float*)d_ws;
    const size_t PQ = (size_t)T_ * R_ * 32;
    float* Pc = ws;
    float* Qc = Pc + PQ;
    float* Pm = Qc + PQ;
    float* Qm = Pm + PQ;

    const size_t A2F = (size_t)96 * NN_;
    const size_t XHF = (size_t)96 * N_ * 4;
    const size_t FULL_NEED = (A2F + XHF + 3 * (size_t)R_ * 64) * 4;
    bool full = ws_size >= FULL_NEED;

    const float* Aall = out + R_;

    if (full) {
        float* A2base = ws;                  // aliases dead P/Q after k_pairall
        float* xhbase = ws + A2F;
        float* state  = xhbase + XHF;
        float* rs     = state + (size_t)R_ * 64;
        float* ub     = rs + (size_t)R_ * 64;

        k_dyall<<<400, 256, 0, stream>>>(x, nf, Ws2d, bs2d, Wrz, brz, Wh, bh,
                                         Wc2, Wm2, Pc, Qc, Pm, Qm, state);
        k_pairall<<<dim3(13, 13, 96), dim3(16, 16), 0, stream>>>(
            Pc, Qc, Pm, Qm, bc2, Wc1, bc1, bm2, Wm1, bm1, out);
        k_a2<<<96 * 16, 256, 0, stream>>>(Aall, A2base, 96);
        k_xh<<<96, 256, 0, stream>>>(Aall, A2base, x, 0, xhbase);

        for (int t = 0; t < T_; ++t) {
            const float* At  = Aall + (size_t)t * 8 * NN_;
            const float* A2t = A2base + (size_t)t * 8 * NN_;
            const float* xht = xhbase + (size_t)t * 8 * N_ * 4;
            k_ru2  <<<200, 256, 0, stream>>>(At, A2t, xht, x, t, state, Wru, bru, rs, ub);
            k_cand2<<<200, 256, 0, stream>>>(At, A2t, xht, x, t, rs, Wcand, bcand, ub, state);
        }
        k_pred<<<R_, 64, 0, stream>>>(state, Wp1, bp1, Wp2, bp2, out);
    } else {
        float* A2base = ws + 4 * PQ;
        float* xhbase = A2base + (size_t)8 * NN_;
        float* state  = xhbase + (size_t)8 * N_ * 4;
        float* rs     = state + (size_t)R_ * 64;
        float* ub     = rs + (size_t)R_ * 64;

        k_dyall<<<400, 256, 0, stream>>>(x, nf, Ws2d, bs2d, Wrz, brz, Wh, bh,
                                         Wc2, Wm2, Pc, Qc, Pm, Qm, state);
        k_pairall<<<dim3(13, 13, 96), dim3(16, 16), 0, stream>>>(
            Pc, Qc, Pm, Qm, bc2, Wc1, bc1, bm2, Wm1, bm1, out);
        for (int t = 0; t < T_; ++t) {
            const float* At = Aall + (size_t)t * 8 * NN_;
            k_a2<<<8 * 16, 256, 0, stream>>>(At, A2base, 8);
            k_xh<<<8, 256, 0, stream>>>(At, A2base, x, t * 8, xhbase);
            k_ru2  <<<200, 256, 0, stream>>>(At, A2base, xhbase, x, t, state, Wru, bru, rs, ub);
            k_cand2<<<200, 256, 0, stream>>>(At, A2base, xhbase, x, t, rs, Wcand, bcand, ub, state);
        }
        k_pred<<<R_, 64, 0, stream>>>(state, Wp1, bp1, Wp2, bp2, out);
    }
}